// Round 5
// baseline (203.403 us; speedup 1.0000x reference)
//
#include <hip/hip_runtime.h>
#include <math.h>
#include <stdint.h>

#define BDIM 8
#define TDIM 2048
#define EDIM 1024
#define HDIM 64
#define NCHUNK 144   // sum over iq of ceil((iq+1)/4), iq in [0,32)

typedef short bf16x8 __attribute__((ext_vector_type(8)));   // 8 bf16 (4 VGPRs)
typedef float f32x4 __attribute__((ext_vector_type(4)));    // 4 fp32 acc

__device__ __forceinline__ unsigned short f2bf(float f) {   // RNE fp32->bf16
    uint32_t u = __builtin_bit_cast(uint32_t, f);
    u += 0x7fffu + ((u >> 16) & 1u);
    return (unsigned short)(u >> 16);
}

// ---------------------------------------------------------------------------
// prep_w: W[e][h] fp32 -> WT[h][e] bf16  (so proj B-frags are contiguous)
// ---------------------------------------------------------------------------
__global__ __launch_bounds__(256) void prep_w(
    const float* __restrict__ Wq, const float* __restrict__ Wk,
    const float* __restrict__ Wv,
    unsigned short* __restrict__ WqT, unsigned short* __restrict__ WkT,
    unsigned short* __restrict__ WvT)
{
    int id = blockIdx.x * 256 + threadIdx.x;   // 0..65535
    int e = id >> 6, h = id & 63;              // coalesced reads
    int oi = h * EDIM + e;
    WqT[oi] = f2bf(Wq[id]);
    WkT[oi] = f2bf(Wk[id]);
    WvT[oi] = f2bf(Wv[id]);
}

// ---------------------------------------------------------------------------
// proj: Q/K/V = x@W + b via bf16 MFMA.  Grid 256 blocks, 256 thr.
// Only x goes through LDS (double-buffered, ONE barrier/iter).  W B-frags
// load straight from global WT[h][e] (L1/L2-resident, 24 KB/iter/CU).
// Q,K stored row-major [b*T][h]; V stored TRANSPOSED [b][d][T].
// ---------------------------------------------------------------------------
__global__ __launch_bounds__(256) void proj_kernel(
    const float* __restrict__ x,
    const unsigned short* __restrict__ WqT, const unsigned short* __restrict__ WkT,
    const unsigned short* __restrict__ WvT,
    const float* __restrict__ bq, const float* __restrict__ bk,
    const float* __restrict__ bv,
    unsigned short* __restrict__ Qb, unsigned short* __restrict__ Kb,
    unsigned short* __restrict__ VbT)
{
    __shared__ unsigned short Xs[2][64][72];   // row stride 144B (16B mult)

    const int t = threadIdx.x;
    const int lane = t & 63, w = t >> 6, quad = lane >> 4, ln = lane & 15;
    const int row0 = blockIdx.x * 64;
    const int sr = t >> 2;              // staging row 0..63
    const int sc = (t & 3) << 4;        // staging col 0,16,32,48

    f32x4 accq[4], acck[4], accv[4];
#pragma unroll
    for (int j = 0; j < 4; ++j) {
        accq[j] = (f32x4)(0.f); acck[j] = (f32x4)(0.f); accv[j] = (f32x4)(0.f);
    }

    // ---- preload tile 0 into Xs[0] ----
    {
        const float* xp = &x[(size_t)(row0 + sr) * EDIM + sc];
        float4 x0 = *(const float4*)(xp);
        float4 x1 = *(const float4*)(xp + 4);
        float4 x2 = *(const float4*)(xp + 8);
        float4 x3 = *(const float4*)(xp + 12);
        bf16x8 xb0, xb1;
        xb0[0]=(short)f2bf(x0.x); xb0[1]=(short)f2bf(x0.y); xb0[2]=(short)f2bf(x0.z); xb0[3]=(short)f2bf(x0.w);
        xb0[4]=(short)f2bf(x1.x); xb0[5]=(short)f2bf(x1.y); xb0[6]=(short)f2bf(x1.z); xb0[7]=(short)f2bf(x1.w);
        xb1[0]=(short)f2bf(x2.x); xb1[1]=(short)f2bf(x2.y); xb1[2]=(short)f2bf(x2.z); xb1[3]=(short)f2bf(x2.w);
        xb1[4]=(short)f2bf(x3.x); xb1[5]=(short)f2bf(x3.y); xb1[6]=(short)f2bf(x3.z); xb1[7]=(short)f2bf(x3.w);
        *(bf16x8*)&Xs[0][sr][sc]     = xb0;
        *(bf16x8*)&Xs[0][sr][sc + 8] = xb1;
    }

    for (int kt = 0; kt < EDIM / 64; ++kt) {
        const int cur = kt & 1, nxt = cur ^ 1;

        // ---- prefetch next x tile to registers (before the barrier) ----
        float4 x0, x1, x2, x3;
        if (kt < 15) {
            const float* xp = &x[(size_t)(row0 + sr) * EDIM + (kt + 1) * 64 + sc];
            x0 = *(const float4*)(xp);
            x1 = *(const float4*)(xp + 4);
            x2 = *(const float4*)(xp + 8);
            x3 = *(const float4*)(xp + 12);
        }

        __syncthreads();   // Xs[cur] fully written (prev iter / preload)

        bf16x8 xa0 = *(const bf16x8*)&Xs[cur][16 * w + ln][8 * quad];
        bf16x8 xa1 = *(const bf16x8*)&Xs[cur][16 * w + ln][32 + 8 * quad];

        const size_t wkb = (size_t)kt * 64 + 8 * quad;   // k-offset within W row
#pragma unroll
        for (int j = 0; j < 4; ++j) {
            const size_t wrow = (size_t)(16 * j + ln) * EDIM + wkb;
            bf16x8 w0, w1;
            w0 = *(const bf16x8*)&WqT[wrow];
            w1 = *(const bf16x8*)&WqT[wrow + 32];
            accq[j] = __builtin_amdgcn_mfma_f32_16x16x32_bf16(xa0, w0, accq[j], 0, 0, 0);
            accq[j] = __builtin_amdgcn_mfma_f32_16x16x32_bf16(xa1, w1, accq[j], 0, 0, 0);
            w0 = *(const bf16x8*)&WkT[wrow];
            w1 = *(const bf16x8*)&WkT[wrow + 32];
            acck[j] = __builtin_amdgcn_mfma_f32_16x16x32_bf16(xa0, w0, acck[j], 0, 0, 0);
            acck[j] = __builtin_amdgcn_mfma_f32_16x16x32_bf16(xa1, w1, acck[j], 0, 0, 0);
            w0 = *(const bf16x8*)&WvT[wrow];
            w1 = *(const bf16x8*)&WvT[wrow + 32];
            accv[j] = __builtin_amdgcn_mfma_f32_16x16x32_bf16(xa0, w0, accv[j], 0, 0, 0);
            accv[j] = __builtin_amdgcn_mfma_f32_16x16x32_bf16(xa1, w1, accv[j], 0, 0, 0);
        }

        // ---- convert + write next tile (read in kt+1 after its barrier) ----
        if (kt < 15) {
            bf16x8 xb0, xb1;
            xb0[0]=(short)f2bf(x0.x); xb0[1]=(short)f2bf(x0.y); xb0[2]=(short)f2bf(x0.z); xb0[3]=(short)f2bf(x0.w);
            xb0[4]=(short)f2bf(x1.x); xb0[5]=(short)f2bf(x1.y); xb0[6]=(short)f2bf(x1.z); xb0[7]=(short)f2bf(x1.w);
            xb1[0]=(short)f2bf(x2.x); xb1[1]=(short)f2bf(x2.y); xb1[2]=(short)f2bf(x2.z); xb1[3]=(short)f2bf(x2.w);
            xb1[4]=(short)f2bf(x3.x); xb1[5]=(short)f2bf(x3.y); xb1[6]=(short)f2bf(x3.z); xb1[7]=(short)f2bf(x3.w);
            *(bf16x8*)&Xs[nxt][sr][sc]     = xb0;
            *(bf16x8*)&Xs[nxt][sr][sc + 8] = xb1;
        }
    }

    // epilogue: bias + bf16 store (C/D layout: row=4*quad+reg, col=ln+16j)
#pragma unroll
    for (int j = 0; j < 4; ++j) {
        int col = 16 * j + ln;
        float bqv = bq[col], bkv = bk[col], bvv = bv[col];
#pragma unroll
        for (int r = 0; r < 4; ++r) {
            size_t row = (size_t)(row0 + 16 * w + 4 * quad + r);
            Qb[row * HDIM + col] = f2bf(accq[j][r] + bqv);
            Kb[row * HDIM + col] = f2bf(acck[j][r] + bkv);
            int bb = (int)(row >> 11);            // row / TDIM
            int tr = (int)(row & 2047);           // row % TDIM
            VbT[((size_t)bb * HDIM + col) * TDIM + tr] = f2bf(accv[j][r] + bvv);
        }
    }
}

// ---------------------------------------------------------------------------
// Split-K flash partial — BARRIER-FREE.  Grid (NCHUNK=144, B).
// K-frags and V-frags load straight from global (K row-major == B-frag
// pattern; VbT[b][d][T] == B-frag pattern for PV).  Only Ps (wave-private
// strip) uses LDS -> zero __syncthreads, LDS 9.2 KB.
// ---------------------------------------------------------------------------
__global__ __launch_bounds__(256) void attn_partial(
    const unsigned short* __restrict__ Qb, const unsigned short* __restrict__ Kb,
    const unsigned short* __restrict__ VbT,
    float* __restrict__ PO, float* __restrict__ Pm, float* __restrict__ Pl)
{
    __shared__ unsigned short Ps[64][72];    // [q][k] bf16, wave-private strips

    const int t = threadIdx.x;
    const int lane = t & 63, w = t >> 6, quad = lane >> 4, ln = lane & 15;
    const int f = blockIdx.x;
    const int b = blockIdx.y;

    // decode (iq, chunk) from f: group g = iq>>2 has (g+1) chunks/q-tile
    int g = 0;
    while (f >= 2 * (g + 1) * (g + 2)) ++g;       // g in 0..7
    const int r_  = f - 2 * g * (g + 1);
    const int iq  = 4 * g + r_ / (g + 1);
    const int ch  = r_ % (g + 1);

    const int q0 = iq * 64;
    const size_t base = (size_t)b * TDIM * HDIM;

    const size_t qrow = base + (size_t)(q0 + 16 * w + ln) * HDIM;
    bf16x8 qa0 = *(const bf16x8*)&Qb[qrow + 8 * quad];
    bf16x8 qa1 = *(const bf16x8*)&Qb[qrow + 32 + 8 * quad];

    f32x4 od[4];
#pragma unroll
    for (int j = 0; j < 4; ++j) od[j] = (f32x4)(0.f);
    float mrow[4], lrow[4];
#pragma unroll
    for (int r = 0; r < 4; ++r) { mrow[r] = -INFINITY; lrow[r] = 0.f; }

    const float scale = 0.125f;   // 1/sqrt(64)
    int j1 = 4 * ch + 3; if (j1 > iq) j1 = iq;

    for (int jt = 4 * ch; jt <= j1; ++jt) {
        // ---- S = Q K^T (K B-frags direct from global) ----
        f32x4 s[4];
#pragma unroll
        for (int j = 0; j < 4; ++j) {
            const size_t krow = base + (size_t)(jt * 64 + 16 * j + ln) * HDIM;
            bf16x8 kb0 = *(const bf16x8*)&Kb[krow + 8 * quad];
            bf16x8 kb1 = *(const bf16x8*)&Kb[krow + 32 + 8 * quad];
            s[j] = (f32x4)(0.f);
            s[j] = __builtin_amdgcn_mfma_f32_16x16x32_bf16(qa0, kb0, s[j], 0, 0, 0);
            s[j] = __builtin_amdgcn_mfma_f32_16x16x32_bf16(qa1, kb1, s[j], 0, 0, 0);
        }

        // ---- scale + causal mask (diagonal tile only) ----
        if (jt == iq) {
#pragma unroll
            for (int j = 0; j < 4; ++j) {
                int kg = jt * 64 + 16 * j + ln;
#pragma unroll
                for (int r = 0; r < 4; ++r) {
                    int qg = q0 + 16 * w + 4 * quad + r;
                    s[j][r] = (kg <= qg) ? s[j][r] * scale : -INFINITY;
                }
            }
        } else {
#pragma unroll
            for (int j = 0; j < 4; ++j)
#pragma unroll
                for (int r = 0; r < 4; ++r) s[j][r] *= scale;
        }

        // ---- online softmax (reduce across 16-lane quad) ----
        float mx[4];
#pragma unroll
        for (int r = 0; r < 4; ++r)
            mx[r] = fmaxf(fmaxf(s[0][r], s[1][r]), fmaxf(s[2][r], s[3][r]));
#pragma unroll
        for (int d = 1; d < 16; d <<= 1)
#pragma unroll
            for (int r = 0; r < 4; ++r)
                mx[r] = fmaxf(mx[r], __shfl_xor(mx[r], d));

        float al[4], rs[4];
#pragma unroll
        for (int r = 0; r < 4; ++r) {
            float mn = fmaxf(mrow[r], mx[r]);
            al[r] = __expf(mrow[r] - mn);
            mrow[r] = mn;
            float p0 = __expf(s[0][r] - mn);
            float p1 = __expf(s[1][r] - mn);
            float p2 = __expf(s[2][r] - mn);
            float p3 = __expf(s[3][r] - mn);
            s[0][r] = p0; s[1][r] = p1; s[2][r] = p2; s[3][r] = p3;
            rs[r] = (p0 + p1) + (p2 + p3);
        }
#pragma unroll
        for (int d = 1; d < 16; d <<= 1)
#pragma unroll
            for (int r = 0; r < 4; ++r)
                rs[r] += __shfl_xor(rs[r], d);
#pragma unroll
        for (int r = 0; r < 4; ++r) lrow[r] = lrow[r] * al[r] + rs[r];

        // ---- rescale O, P -> LDS (wave-private strip, no barrier) ----
#pragma unroll
        for (int j = 0; j < 4; ++j)
#pragma unroll
            for (int r = 0; r < 4; ++r) {
                od[j][r] *= al[r];
                Ps[16 * w + 4 * quad + r][16 * j + ln] = f2bf(s[j][r]);
            }

        // ---- O += P V (V B-frags direct from global VbT) ----
        bf16x8 pa0 = *(const bf16x8*)&Ps[16 * w + ln][8 * quad];
        bf16x8 pa1 = *(const bf16x8*)&Ps[16 * w + ln][32 + 8 * quad];
#pragma unroll
        for (int j = 0; j < 4; ++j) {
            const size_t vrow = ((size_t)b * HDIM + 16 * j + ln) * TDIM + jt * 64;
            bf16x8 vb0 = *(const bf16x8*)&VbT[vrow + 8 * quad];
            bf16x8 vb1 = *(const bf16x8*)&VbT[vrow + 32 + 8 * quad];
            od[j] = __builtin_amdgcn_mfma_f32_16x16x32_bf16(pa0, vb0, od[j], 0, 0, 0);
            od[j] = __builtin_amdgcn_mfma_f32_16x16x32_bf16(pa1, vb1, od[j], 0, 0, 0);
        }
    }

    // ---- write partial (unnormalized O, m, l) ----
    const size_t p = (size_t)b * NCHUNK + f;
#pragma unroll
    for (int j = 0; j < 4; ++j)
#pragma unroll
        for (int r = 0; r < 4; ++r)
            PO[p * 4096 + (size_t)(16 * w + 4 * quad + r) * 64 + 16 * j + ln] = od[j][r];
    if (ln == 0) {
#pragma unroll
        for (int r = 0; r < 4; ++r) {
            Pm[p * 64 + 16 * w + 4 * quad + r] = mrow[r];
            Pl[p * 64 + 16 * w + 4 * quad + r] = lrow[r];
        }
    }
}

// ---------------------------------------------------------------------------
// Combine partials.  Grid (T/64, B), 256 thr.  Thread t: row=t>>2,
// cols (t&3)*16..+15.  nchunks = (iq>>2)+1 <= 8.
// ---------------------------------------------------------------------------
__global__ __launch_bounds__(256) void attn_combine(
    const float* __restrict__ PO, const float* __restrict__ Pm,
    const float* __restrict__ Pl, float* __restrict__ out)
{
    const int iq = blockIdx.x, b = blockIdx.y;
    const int g = iq >> 2;
    const int nch = g + 1;
    const int fbase = 2 * g * (g + 1) + (iq - 4 * g) * (g + 1);
    const int t = threadIdx.x;
    const int row = t >> 2;
    const int c0 = (t & 3) << 4;
    const size_t pbase = (size_t)b * NCHUNK + fbase;

    float M = -INFINITY;
    for (int c = 0; c < nch; ++c)
        M = fmaxf(M, Pm[(pbase + c) * 64 + row]);

    float4 a0 = {0,0,0,0}, a1 = {0,0,0,0}, a2 = {0,0,0,0}, a3 = {0,0,0,0};
    float L = 0.f;
    for (int c = 0; c < nch; ++c) {
        size_t p = pbase + c;
        float sc = __expf(Pm[p * 64 + row] - M);
        L += sc * Pl[p * 64 + row];
        const float* po = &PO[p * 4096 + (size_t)row * 64 + c0];
        float4 v0 = *(const float4*)(po);
        float4 v1 = *(const float4*)(po + 4);
        float4 v2 = *(const float4*)(po + 8);
        float4 v3 = *(const float4*)(po + 12);
        a0.x += sc*v0.x; a0.y += sc*v0.y; a0.z += sc*v0.z; a0.w += sc*v0.w;
        a1.x += sc*v1.x; a1.y += sc*v1.y; a1.z += sc*v1.z; a1.w += sc*v1.w;
        a2.x += sc*v2.x; a2.y += sc*v2.y; a2.z += sc*v2.z; a2.w += sc*v2.w;
        a3.x += sc*v3.x; a3.y += sc*v3.y; a3.z += sc*v3.z; a3.w += sc*v3.w;
    }
    float li = 1.f / L;
    a0.x*=li; a0.y*=li; a0.z*=li; a0.w*=li;
    a1.x*=li; a1.y*=li; a1.z*=li; a1.w*=li;
    a2.x*=li; a2.y*=li; a2.z*=li; a2.w*=li;
    a3.x*=li; a3.y*=li; a3.z*=li; a3.w*=li;
    float* op = &out[((size_t)b * TDIM + (size_t)iq * 64 + row) * HDIM + c0];
    *(float4*)(op)      = a0;
    *(float4*)(op + 4)  = a1;
    *(float4*)(op + 8)  = a2;
    *(float4*)(op + 12) = a3;
}

extern "C" void kernel_launch(void* const* d_in, const int* in_sizes, int n_in,
                              void* d_out, int out_size, void* d_ws, size_t ws_size,
                              hipStream_t stream) {
    const float* x  = (const float*)d_in[0];
    const float* Wq = (const float*)d_in[1];
    const float* bq = (const float*)d_in[2];
    const float* Wk = (const float*)d_in[3];
    const float* bk = (const float*)d_in[4];
    const float* Wv = (const float*)d_in[5];
    const float* bv = (const float*)d_in[6];
    float* out = (float*)d_out;

    const size_t n = (size_t)BDIM * TDIM * HDIM;     // 1,048,576
    unsigned short* Qb  = (unsigned short*)d_ws;
    unsigned short* Kb  = Qb + n;
    unsigned short* VbT = Kb + n;
    unsigned short* WqT = VbT + n;
    unsigned short* WkT = WqT + (size_t)EDIM * HDIM;
    unsigned short* WvT = WkT + (size_t)EDIM * HDIM;
    float* PO = (float*)(WvT + (size_t)EDIM * HDIM);           // 1152*4096 f32
    float* Pm = PO + (size_t)BDIM * NCHUNK * 4096;             // 1152*64
    float* Pl = Pm + (size_t)BDIM * NCHUNK * 64;

    prep_w<<<dim3(EDIM * HDIM / 256), 256, 0, stream>>>(Wq, Wk, Wv, WqT, WkT, WvT);
    proj_kernel<<<dim3(BDIM * TDIM / 64), 256, 0, stream>>>(
        x, WqT, WkT, WvT, bq, bk, bv, Qb, Kb, VbT);
    attn_partial<<<dim3(NCHUNK, BDIM), 256, 0, stream>>>(Qb, Kb, VbT, PO, Pm, Pl);
    attn_combine<<<dim3(TDIM / 64, BDIM), 256, 0, stream>>>(PO, Pm, Pl, out);
}

// Round 6
// 151.303 us; speedup vs baseline: 1.3443x; 1.3443x over previous
//
#include <hip/hip_runtime.h>
#include <math.h>
#include <stdint.h>

#define BDIM 8
#define TDIM 2048
#define EDIM 1024
#define HDIM 64
#define NCHUNK 144   // sum over iq of ceil((iq+1)/4), iq in [0,32)

typedef short bf16x8 __attribute__((ext_vector_type(8)));   // 8 bf16 (4 VGPRs)
typedef float f32x4 __attribute__((ext_vector_type(4)));    // 4 fp32 acc

__device__ __forceinline__ unsigned short f2bf(float f) {   // RNE fp32->bf16
    uint32_t u = __builtin_bit_cast(uint32_t, f);
    u += 0x7fffu + ((u >> 16) & 1u);
    return (unsigned short)(u >> 16);
}

// ---------------------------------------------------------------------------
// prep_w: W[e][h] fp32 -> WT[h][e] bf16  (so proj W-tile staging is
// row-contiguous 16B loads)
// ---------------------------------------------------------------------------
__global__ __launch_bounds__(256) void prep_w(
    const float* __restrict__ Wq, const float* __restrict__ Wk,
    const float* __restrict__ Wv,
    unsigned short* __restrict__ WqT, unsigned short* __restrict__ WkT,
    unsigned short* __restrict__ WvT)
{
    int id = blockIdx.x * 256 + threadIdx.x;   // 0..65535
    int e = id >> 6, h = id & 63;              // coalesced reads
    int oi = h * EDIM + e;
    WqT[oi] = f2bf(Wq[id]);
    WkT[oi] = f2bf(Wk[id]);
    WvT[oi] = f2bf(Wv[id]);
}

// ---------------------------------------------------------------------------
// proj: Q/K/V = x@W + b via bf16 MFMA.  Grid 256 blocks (1/CU!), 256 thr.
// Since TLP is nil (1 wave/SIMD), hide latency with ILP: double-buffer ALL
// LDS tiles (x + 3 W = 73.7 KB), prefetch next tiles to registers during the
// MFMA phase, ONE barrier per K-iter.
// Q,K stored row-major [b*T][h]; V stored TRANSPOSED [b][d][T].
// ---------------------------------------------------------------------------
__global__ __launch_bounds__(256) void proj_kernel(
    const float* __restrict__ x,
    const unsigned short* __restrict__ WqT, const unsigned short* __restrict__ WkT,
    const unsigned short* __restrict__ WvT,
    const float* __restrict__ bq, const float* __restrict__ bk,
    const float* __restrict__ bv,
    unsigned short* __restrict__ Qb, unsigned short* __restrict__ Kb,
    unsigned short* __restrict__ VbT)
{
    __shared__ unsigned short Xs[2][64][72];   // row stride 144B (16B mult)
    __shared__ unsigned short Wqs[2][64][72];
    __shared__ unsigned short Wks[2][64][72];
    __shared__ unsigned short Wvs[2][64][72];

    const int t = threadIdx.x;
    const int lane = t & 63, w = t >> 6, quad = lane >> 4, ln = lane & 15;
    const int row0 = blockIdx.x * 64;
    const int sr = t >> 2;              // staging row 0..63
    const int sc = (t & 3) << 4;        // staging col 0,16,32,48

    f32x4 accq[4], acck[4], accv[4];
#pragma unroll
    for (int j = 0; j < 4; ++j) {
        accq[j] = (f32x4)(0.f); acck[j] = (f32x4)(0.f); accv[j] = (f32x4)(0.f);
    }

    const float*          xp0 = &x[(size_t)(row0 + sr) * EDIM + sc];
    const unsigned short* wp  = (const unsigned short*)0;   // set per use
    const size_t wrow = (size_t)sr * EDIM + sc;

    // ---- preload tile 0 into buf 0 ----
    {
        float4 x0 = *(const float4*)(xp0);
        float4 x1 = *(const float4*)(xp0 + 4);
        float4 x2 = *(const float4*)(xp0 + 8);
        float4 x3 = *(const float4*)(xp0 + 12);
        bf16x8 xb0, xb1;
        xb0[0]=(short)f2bf(x0.x); xb0[1]=(short)f2bf(x0.y); xb0[2]=(short)f2bf(x0.z); xb0[3]=(short)f2bf(x0.w);
        xb0[4]=(short)f2bf(x1.x); xb0[5]=(short)f2bf(x1.y); xb0[6]=(short)f2bf(x1.z); xb0[7]=(short)f2bf(x1.w);
        xb1[0]=(short)f2bf(x2.x); xb1[1]=(short)f2bf(x2.y); xb1[2]=(short)f2bf(x2.z); xb1[3]=(short)f2bf(x2.w);
        xb1[4]=(short)f2bf(x3.x); xb1[5]=(short)f2bf(x3.y); xb1[6]=(short)f2bf(x3.z); xb1[7]=(short)f2bf(x3.w);
        *(bf16x8*)&Xs[0][sr][sc]     = xb0;
        *(bf16x8*)&Xs[0][sr][sc + 8] = xb1;
        *(bf16x8*)&Wqs[0][sr][sc]     = *(const bf16x8*)&WqT[wrow];
        *(bf16x8*)&Wqs[0][sr][sc + 8] = *(const bf16x8*)&WqT[wrow + 8];
        *(bf16x8*)&Wks[0][sr][sc]     = *(const bf16x8*)&WkT[wrow];
        *(bf16x8*)&Wks[0][sr][sc + 8] = *(const bf16x8*)&WkT[wrow + 8];
        *(bf16x8*)&Wvs[0][sr][sc]     = *(const bf16x8*)&WvT[wrow];
        *(bf16x8*)&Wvs[0][sr][sc + 8] = *(const bf16x8*)&WvT[wrow + 8];
    }

    for (int kt = 0; kt < EDIM / 64; ++kt) {
        const int cur = kt & 1, nxt = cur ^ 1;

        // ---- issue next-tile global loads (in flight during MFMA) ----
        float4 x0, x1, x2, x3;
        bf16x8 wq0, wq1, wk0, wk1, wv0, wv1;
        if (kt < 15) {
            const float* xp = xp0 + (kt + 1) * 64;
            x0 = *(const float4*)(xp);
            x1 = *(const float4*)(xp + 4);
            x2 = *(const float4*)(xp + 8);
            x3 = *(const float4*)(xp + 12);
            const size_t wo = wrow + (kt + 1) * 64;
            wq0 = *(const bf16x8*)&WqT[wo];
            wq1 = *(const bf16x8*)&WqT[wo + 8];
            wk0 = *(const bf16x8*)&WkT[wo];
            wk1 = *(const bf16x8*)&WkT[wo + 8];
            wv0 = *(const bf16x8*)&WvT[wo];
            wv1 = *(const bf16x8*)&WvT[wo + 8];
        }

        __syncthreads();   // buf[cur] fully written (prev iter / preload)

        bf16x8 xa0 = *(const bf16x8*)&Xs[cur][16 * w + ln][8 * quad];
        bf16x8 xa1 = *(const bf16x8*)&Xs[cur][16 * w + ln][32 + 8 * quad];
#pragma unroll
        for (int j = 0; j < 4; ++j) {
            bf16x8 w0, w1;
            w0 = *(const bf16x8*)&Wqs[cur][16 * j + ln][8 * quad];
            w1 = *(const bf16x8*)&Wqs[cur][16 * j + ln][32 + 8 * quad];
            accq[j] = __builtin_amdgcn_mfma_f32_16x16x32_bf16(xa0, w0, accq[j], 0, 0, 0);
            accq[j] = __builtin_amdgcn_mfma_f32_16x16x32_bf16(xa1, w1, accq[j], 0, 0, 0);
            w0 = *(const bf16x8*)&Wks[cur][16 * j + ln][8 * quad];
            w1 = *(const bf16x8*)&Wks[cur][16 * j + ln][32 + 8 * quad];
            acck[j] = __builtin_amdgcn_mfma_f32_16x16x32_bf16(xa0, w0, acck[j], 0, 0, 0);
            acck[j] = __builtin_amdgcn_mfma_f32_16x16x32_bf16(xa1, w1, acck[j], 0, 0, 0);
            w0 = *(const bf16x8*)&Wvs[cur][16 * j + ln][8 * quad];
            w1 = *(const bf16x8*)&Wvs[cur][16 * j + ln][32 + 8 * quad];
            accv[j] = __builtin_amdgcn_mfma_f32_16x16x32_bf16(xa0, w0, accv[j], 0, 0, 0);
            accv[j] = __builtin_amdgcn_mfma_f32_16x16x32_bf16(xa1, w1, accv[j], 0, 0, 0);
        }

        // ---- convert + write next tile to alternate buffer (no barrier:
        //      buf[nxt] readers all passed this iteration's barrier) ----
        if (kt < 15) {
            bf16x8 xb0, xb1;
            xb0[0]=(short)f2bf(x0.x); xb0[1]=(short)f2bf(x0.y); xb0[2]=(short)f2bf(x0.z); xb0[3]=(short)f2bf(x0.w);
            xb0[4]=(short)f2bf(x1.x); xb0[5]=(short)f2bf(x1.y); xb0[6]=(short)f2bf(x1.z); xb0[7]=(short)f2bf(x1.w);
            xb1[0]=(short)f2bf(x2.x); xb1[1]=(short)f2bf(x2.y); xb1[2]=(short)f2bf(x2.z); xb1[3]=(short)f2bf(x2.w);
            xb1[4]=(short)f2bf(x3.x); xb1[5]=(short)f2bf(x3.y); xb1[6]=(short)f2bf(x3.z); xb1[7]=(short)f2bf(x3.w);
            *(bf16x8*)&Xs[nxt][sr][sc]     = xb0;
            *(bf16x8*)&Xs[nxt][sr][sc + 8] = xb1;
            *(bf16x8*)&Wqs[nxt][sr][sc]     = wq0;
            *(bf16x8*)&Wqs[nxt][sr][sc + 8] = wq1;
            *(bf16x8*)&Wks[nxt][sr][sc]     = wk0;
            *(bf16x8*)&Wks[nxt][sr][sc + 8] = wk1;
            *(bf16x8*)&Wvs[nxt][sr][sc]     = wv0;
            *(bf16x8*)&Wvs[nxt][sr][sc + 8] = wv1;
        }
    }

    // epilogue: bias + bf16 store (C/D layout: row=4*quad+reg, col=ln+16j)
#pragma unroll
    for (int j = 0; j < 4; ++j) {
        int col = 16 * j + ln;
        float bqv = bq[col], bkv = bk[col], bvv = bv[col];
#pragma unroll
        for (int r = 0; r < 4; ++r) {
            size_t row = (size_t)(row0 + 16 * w + 4 * quad + r);
            Qb[row * HDIM + col] = f2bf(accq[j][r] + bqv);
            Kb[row * HDIM + col] = f2bf(acck[j][r] + bkv);
            int bb = (int)(row >> 11);            // row / TDIM
            int tr = (int)(row & 2047);           // row % TDIM
            VbT[((size_t)bb * HDIM + col) * TDIM + tr] = f2bf(accv[j][r] + bvv);
        }
    }
}

// ---------------------------------------------------------------------------
// Split-K flash partial (round-4 version: LDS-staged K/V with coalesced
// loads — direct-global frag gathers measurably regress).
// Grid (NCHUNK=144, B).  Each block = one (q-tile iq, K-chunk of 4 tiles).
// ---------------------------------------------------------------------------
__global__ __launch_bounds__(256) void attn_partial(
    const unsigned short* __restrict__ Qb, const unsigned short* __restrict__ Kb,
    const unsigned short* __restrict__ VbT,
    float* __restrict__ PO, float* __restrict__ Pm, float* __restrict__ Pl)
{
    __shared__ unsigned short Ks[64][72];
    __shared__ unsigned short VsT[64][72];   // [d][k]
    __shared__ unsigned short Ps[64][72];    // [q][k] bf16

    const int t = threadIdx.x;
    const int lane = t & 63, w = t >> 6, quad = lane >> 4, ln = lane & 15;
    const int f = blockIdx.x;
    const int b = blockIdx.y;

    // decode (iq, chunk) from f: group g = iq>>2 has (g+1) chunks/q-tile
    int g = 0;
    while (f >= 2 * (g + 1) * (g + 2)) ++g;       // g in 0..7
    const int r_  = f - 2 * g * (g + 1);
    const int iq  = 4 * g + r_ / (g + 1);
    const int ch  = r_ % (g + 1);

    const int q0 = iq * 64;
    const size_t base = (size_t)b * TDIM * HDIM;
    const int sr = t >> 2;
    const int sc = (t & 3) << 4;

    const size_t qrow = base + (size_t)(q0 + 16 * w + ln) * HDIM;
    bf16x8 qa0 = *(const bf16x8*)&Qb[qrow + 8 * quad];
    bf16x8 qa1 = *(const bf16x8*)&Qb[qrow + 32 + 8 * quad];

    f32x4 od[4];
#pragma unroll
    for (int j = 0; j < 4; ++j) od[j] = (f32x4)(0.f);
    float mrow[4], lrow[4];
#pragma unroll
    for (int r = 0; r < 4; ++r) { mrow[r] = -INFINITY; lrow[r] = 0.f; }

    const float scale = 0.125f;   // 1/sqrt(64)
    int j1 = 4 * ch + 3; if (j1 > iq) j1 = iq;

    for (int jt = 4 * ch; jt <= j1; ++jt) {
        __syncthreads();
        {
            size_t ko = base + (size_t)(jt * 64 + sr) * HDIM + sc;
            *(bf16x8*)&Ks[sr][sc]     = *(const bf16x8*)&Kb[ko];
            *(bf16x8*)&Ks[sr][sc + 8] = *(const bf16x8*)&Kb[ko + 8];
            const unsigned short* vrow =
                &VbT[((size_t)b * HDIM + sr) * TDIM + jt * 64 + sc];
            *(bf16x8*)&VsT[sr][sc]     = *(const bf16x8*)vrow;
            *(bf16x8*)&VsT[sr][sc + 8] = *(const bf16x8*)(vrow + 8);
        }
        __syncthreads();

        // ---- S = Q K^T ----
        f32x4 s[4];
#pragma unroll
        for (int j = 0; j < 4; ++j) {
            bf16x8 kb0 = *(const bf16x8*)&Ks[16 * j + ln][8 * quad];
            bf16x8 kb1 = *(const bf16x8*)&Ks[16 * j + ln][32 + 8 * quad];
            s[j] = (f32x4)(0.f);
            s[j] = __builtin_amdgcn_mfma_f32_16x16x32_bf16(qa0, kb0, s[j], 0, 0, 0);
            s[j] = __builtin_amdgcn_mfma_f32_16x16x32_bf16(qa1, kb1, s[j], 0, 0, 0);
        }

        // ---- scale + causal mask (diagonal tile only) ----
        if (jt == iq) {
#pragma unroll
            for (int j = 0; j < 4; ++j) {
                int kg = jt * 64 + 16 * j + ln;
#pragma unroll
                for (int r = 0; r < 4; ++r) {
                    int qg = q0 + 16 * w + 4 * quad + r;
                    s[j][r] = (kg <= qg) ? s[j][r] * scale : -INFINITY;
                }
            }
        } else {
#pragma unroll
            for (int j = 0; j < 4; ++j)
#pragma unroll
                for (int r = 0; r < 4; ++r) s[j][r] *= scale;
        }

        // ---- online softmax (reduce across 16-lane quad) ----
        float mx[4];
#pragma unroll
        for (int r = 0; r < 4; ++r)
            mx[r] = fmaxf(fmaxf(s[0][r], s[1][r]), fmaxf(s[2][r], s[3][r]));
#pragma unroll
        for (int d = 1; d < 16; d <<= 1)
#pragma unroll
            for (int r = 0; r < 4; ++r)
                mx[r] = fmaxf(mx[r], __shfl_xor(mx[r], d));

        float al[4], rs[4];
#pragma unroll
        for (int r = 0; r < 4; ++r) {
            float mn = fmaxf(mrow[r], mx[r]);
            al[r] = __expf(mrow[r] - mn);
            mrow[r] = mn;
            float p0 = __expf(s[0][r] - mn);
            float p1 = __expf(s[1][r] - mn);
            float p2 = __expf(s[2][r] - mn);
            float p3 = __expf(s[3][r] - mn);
            s[0][r] = p0; s[1][r] = p1; s[2][r] = p2; s[3][r] = p3;
            rs[r] = (p0 + p1) + (p2 + p3);
        }
#pragma unroll
        for (int d = 1; d < 16; d <<= 1)
#pragma unroll
            for (int r = 0; r < 4; ++r)
                rs[r] += __shfl_xor(rs[r], d);
#pragma unroll
        for (int r = 0; r < 4; ++r) lrow[r] = lrow[r] * al[r] + rs[r];

        // ---- rescale O, P -> LDS (wave-private strip) ----
#pragma unroll
        for (int j = 0; j < 4; ++j)
#pragma unroll
            for (int r = 0; r < 4; ++r) {
                od[j][r] *= al[r];
                Ps[16 * w + 4 * quad + r][16 * j + ln] = f2bf(s[j][r]);
            }

        // ---- O += P V ----
        bf16x8 pa0 = *(const bf16x8*)&Ps[16 * w + ln][8 * quad];
        bf16x8 pa1 = *(const bf16x8*)&Ps[16 * w + ln][32 + 8 * quad];
#pragma unroll
        for (int j = 0; j < 4; ++j) {
            bf16x8 vb0 = *(const bf16x8*)&VsT[16 * j + ln][8 * quad];
            bf16x8 vb1 = *(const bf16x8*)&VsT[16 * j + ln][32 + 8 * quad];
            od[j] = __builtin_amdgcn_mfma_f32_16x16x32_bf16(pa0, vb0, od[j], 0, 0, 0);
            od[j] = __builtin_amdgcn_mfma_f32_16x16x32_bf16(pa1, vb1, od[j], 0, 0, 0);
        }
    }

    // ---- write partial (unnormalized O, m, l) ----
    const size_t p = (size_t)b * NCHUNK + f;
#pragma unroll
    for (int j = 0; j < 4; ++j)
#pragma unroll
        for (int r = 0; r < 4; ++r)
            PO[p * 4096 + (size_t)(16 * w + 4 * quad + r) * 64 + 16 * j + ln] = od[j][r];
    if (ln == 0) {
#pragma unroll
        for (int r = 0; r < 4; ++r) {
            Pm[p * 64 + 16 * w + 4 * quad + r] = mrow[r];
            Pl[p * 64 + 16 * w + 4 * quad + r] = lrow[r];
        }
    }
}

// ---------------------------------------------------------------------------
// Combine partials.  Grid (T/64, B), 256 thr.  Thread t: row=t>>2,
// cols (t&3)*16..+15.  nchunks = (iq>>2)+1 <= 8.
// ---------------------------------------------------------------------------
__global__ __launch_bounds__(256) void attn_combine(
    const float* __restrict__ PO, const float* __restrict__ Pm,
    const float* __restrict__ Pl, float* __restrict__ out)
{
    const int iq = blockIdx.x, b = blockIdx.y;
    const int g = iq >> 2;
    const int nch = g + 1;
    const int fbase = 2 * g * (g + 1) + (iq - 4 * g) * (g + 1);
    const int t = threadIdx.x;
    const int row = t >> 2;
    const int c0 = (t & 3) << 4;
    const size_t pbase = (size_t)b * NCHUNK + fbase;

    float M = -INFINITY;
    for (int c = 0; c < nch; ++c)
        M = fmaxf(M, Pm[(pbase + c) * 64 + row]);

    float4 a0 = {0,0,0,0}, a1 = {0,0,0,0}, a2 = {0,0,0,0}, a3 = {0,0,0,0};
    float L = 0.f;
    for (int c = 0; c < nch; ++c) {
        size_t p = pbase + c;
        float sc = __expf(Pm[p * 64 + row] - M);
        L += sc * Pl[p * 64 + row];
        const float* po = &PO[p * 4096 + (size_t)row * 64 + c0];
        float4 v0 = *(const float4*)(po);
        float4 v1 = *(const float4*)(po + 4);
        float4 v2 = *(const float4*)(po + 8);
        float4 v3 = *(const float4*)(po + 12);
        a0.x += sc*v0.x; a0.y += sc*v0.y; a0.z += sc*v0.z; a0.w += sc*v0.w;
        a1.x += sc*v1.x; a1.y += sc*v1.y; a1.z += sc*v1.z; a1.w += sc*v1.w;
        a2.x += sc*v2.x; a2.y += sc*v2.y; a2.z += sc*v2.z; a2.w += sc*v2.w;
        a3.x += sc*v3.x; a3.y += sc*v3.y; a3.z += sc*v3.z; a3.w += sc*v3.w;
    }
    float li = 1.f / L;
    a0.x*=li; a0.y*=li; a0.z*=li; a0.w*=li;
    a1.x*=li; a1.y*=li; a1.z*=li; a1.w*=li;
    a2.x*=li; a2.y*=li; a2.z*=li; a2.w*=li;
    a3.x*=li; a3.y*=li; a3.z*=li; a3.w*=li;
    float* op = &out[((size_t)b * TDIM + (size_t)iq * 64 + row) * HDIM + c0];
    *(float4*)(op)      = a0;
    *(float4*)(op + 4)  = a1;
    *(float4*)(op + 8)  = a2;
    *(float4*)(op + 12) = a3;
}

extern "C" void kernel_launch(void* const* d_in, const int* in_sizes, int n_in,
                              void* d_out, int out_size, void* d_ws, size_t ws_size,
                              hipStream_t stream) {
    const float* x  = (const float*)d_in[0];
    const float* Wq = (const float*)d_in[1];
    const float* bq = (const float*)d_in[2];
    const float* Wk = (const float*)d_in[3];
    const float* bk = (const float*)d_in[4];
    const float* Wv = (const float*)d_in[5];
    const float* bv = (const float*)d_in[6];
    float* out = (float*)d_out;

    const size_t n = (size_t)BDIM * TDIM * HDIM;     // 1,048,576
    unsigned short* Qb  = (unsigned short*)d_ws;
    unsigned short* Kb  = Qb + n;
    unsigned short* VbT = Kb + n;
    unsigned short* WqT = VbT + n;
    unsigned short* WkT = WqT + (size_t)EDIM * HDIM;
    unsigned short* WvT = WkT + (size_t)EDIM * HDIM;
    float* PO = (float*)(WvT + (size_t)EDIM * HDIM);           // 1152*4096 f32
    float* Pm = PO + (size_t)BDIM * NCHUNK * 4096;             // 1152*64
    float* Pl = Pm + (size_t)BDIM * NCHUNK * 64;

    prep_w<<<dim3(EDIM * HDIM / 256), 256, 0, stream>>>(Wq, Wk, Wv, WqT, WkT, WvT);
    proj_kernel<<<dim3(BDIM * TDIM / 64), 256, 0, stream>>>(
        x, WqT, WkT, WvT, bq, bk, bv, Qb, Kb, VbT);
    attn_partial<<<dim3(NCHUNK, BDIM), 256, 0, stream>>>(Qb, Kb, VbT, PO, Pm, Pl);
    attn_combine<<<dim3(TDIM / 64, BDIM), 256, 0, stream>>>(PO, Pm, Pl, out);
}